// Round 8
// baseline (1287.268 us; speedup 1.0000x reference)
//
#include <hip/hip_runtime.h>
#include <hip/hip_bf16.h>
#include <math.h>

// Problem constants
#define BB   64
#define TT   256
#define VV   65
#define DD   384
#define HH   6
#define HDD  64
#define LL   6
#define FFD  1536
#define BT   (BB * TT)        // 16384 rows
#define EPSL 1e-5f
#define SCALE 0.05103103630798287f  // 384^-0.5

using bf16x8 = __attribute__((ext_vector_type(8))) short;
using f32x4  = __attribute__((ext_vector_type(4))) float;

__device__ __forceinline__ short f2bf(float f) {
    __hip_bfloat16 h = __float2bfloat16(f);
    return *reinterpret_cast<short*>(&h);
}
__device__ __forceinline__ float bf2f(short s) {
    union { unsigned u; float f; } c;
    c.u = ((unsigned)(unsigned short)s) << 16;
    return c.f;
}

__device__ __forceinline__ void load_lds16(const void* g, void* lds_base) {
    __builtin_amdgcn_global_load_lds(
        (const __attribute__((address_space(1))) void*)g,
        (__attribute__((address_space(3))) void*)lds_base,
        16, 0, 0);
}

// ---------------------------------------------------------------------------
// Embedding -> bf16 x.  Thread handles 8 elems: 2 float4 reads each of tok/pos.
// ---------------------------------------------------------------------------
__global__ __launch_bounds__(256) void embed_k(const int* __restrict__ idx,
                                               const float* __restrict__ tok,
                                               const float* __restrict__ pos,
                                               short* __restrict__ x) {
    int i = blockIdx.x * 256 + threadIdx.x;     // BT*48 threads
    int bt = i / 48;
    int g  = i - bt * 48;
    int t  = bt & (TT - 1);
    const float4* tp = (const float4*)tok + (size_t)idx[bt] * 96 + g * 2;
    const float4* pp = (const float4*)pos + (size_t)t * 96 + g * 2;
    float4 a0 = tp[0], a1 = tp[1], p0 = pp[0], p1 = pp[1];
    bf16x8 o;
    o[0] = f2bf(a0.x + p0.x); o[1] = f2bf(a0.y + p0.y);
    o[2] = f2bf(a0.z + p0.z); o[3] = f2bf(a0.w + p0.w);
    o[4] = f2bf(a1.x + p1.x); o[5] = f2bf(a1.y + p1.y);
    o[6] = f2bf(a1.z + p1.z); o[7] = f2bf(a1.w + p1.w);
    *reinterpret_cast<bf16x8*>(x + (size_t)bt * DD + g * 8) = o;
}

// ---------------------------------------------------------------------------
// LayerNorm bf16 in -> bf16 out. One wave per row of 384; block = 4 rows.
// Vectorized as dword (2xbf16) loads/stores.
// ---------------------------------------------------------------------------
__global__ __launch_bounds__(256) void ln_k(const short* __restrict__ in,
                                            const float* __restrict__ w,
                                            const float* __restrict__ b,
                                            short* __restrict__ out) {
    int row  = blockIdx.x * 4 + (threadIdx.x >> 6);
    int lane = threadIdx.x & 63;
    const unsigned* pu = (const unsigned*)(in + (size_t)row * DD);
    unsigned u0 = pu[lane], u1 = pu[lane + 64], u2 = pu[lane + 128];
    float v00 = bf2f((short)(u0 & 0xffff)), v01 = bf2f((short)(u0 >> 16));
    float v10 = bf2f((short)(u1 & 0xffff)), v11 = bf2f((short)(u1 >> 16));
    float v20 = bf2f((short)(u2 & 0xffff)), v21 = bf2f((short)(u2 >> 16));
    float s = v00 + v01 + v10 + v11 + v20 + v21;
#pragma unroll
    for (int off = 32; off; off >>= 1) s += __shfl_xor(s, off);
    float mean = s * (1.0f / DD);
    float d00 = v00 - mean, d01 = v01 - mean, d10 = v10 - mean,
          d11 = v11 - mean, d20 = v20 - mean, d21 = v21 - mean;
    float s2 = d00*d00 + d01*d01 + d10*d10 + d11*d11 + d20*d20 + d21*d21;
#pragma unroll
    for (int off = 32; off; off >>= 1) s2 += __shfl_xor(s2, off);
    float rstd = rsqrtf(s2 * (1.0f / DD) + EPSL);
    int c0 = lane * 2, c1 = c0 + 128, c2 = c0 + 256;
    unsigned* po = (unsigned*)(out + (size_t)row * DD);
    unsigned r0 = (unsigned)(unsigned short)f2bf(d00 * rstd * w[c0] + b[c0]) |
                  ((unsigned)(unsigned short)f2bf(d01 * rstd * w[c0+1] + b[c0+1]) << 16);
    unsigned r1 = (unsigned)(unsigned short)f2bf(d10 * rstd * w[c1] + b[c1]) |
                  ((unsigned)(unsigned short)f2bf(d11 * rstd * w[c1+1] + b[c1+1]) << 16);
    unsigned r2 = (unsigned)(unsigned short)f2bf(d20 * rstd * w[c2] + b[c2]) |
                  ((unsigned)(unsigned short)f2bf(d21 * rstd * w[c2+1] + b[c2+1]) << 16);
    po[lane] = r0; po[lane + 64] = r1; po[lane + 128] = r2;
}

// ---------------------------------------------------------------------------
// Weight transpose+convert: W[K][N] f32 -> Wt[Npad][K] bf16
// ---------------------------------------------------------------------------
__global__ __launch_bounds__(256) void wconv_k(const float* __restrict__ W,
                                               short* __restrict__ Wt,
                                               int K, int N, int Npad) {
    __shared__ float tile[32][33];
    W  += (size_t)blockIdx.z * K * N;
    Wt += (size_t)blockIdx.z * Npad * K;
    const int t  = threadIdx.x;
    const int c  = t & 31;
    const int r8 = t >> 5;
    const int k0 = blockIdx.y * 32;
    const int n0 = blockIdx.x * 32;
#pragma unroll
    for (int p = 0; p < 4; ++p) {
        int kk = r8 + 8 * p;
        int n  = n0 + c;
        tile[kk][c] = (n < N) ? W[(size_t)(k0 + kk) * N + n] : 0.f;
    }
    __syncthreads();
#pragma unroll
    for (int p = 0; p < 4; ++p) {
        int nl = r8 + 8 * p;
        Wt[(size_t)(n0 + nl) * K + k0 + c] = f2bf(tile[c][nl]);
    }
}

// ---------------------------------------------------------------------------
// QKV weight convert -> WqkvT [L][1152][384] bf16
// ---------------------------------------------------------------------------
__global__ __launch_bounds__(256) void qkvconv_k(const float* __restrict__ wq,
                                                 const float* __restrict__ wk,
                                                 const float* __restrict__ wv,
                                                 short* __restrict__ Wt) {
    int tid = blockIdx.x * 256 + threadIdx.x;
    int e  = tid & 63;
    int k  = (tid >> 6) % 384;
    int r2 = (tid >> 6) / 384;
    int h  = r2 % 6;
    int r3 = r2 / 6;
    int part = r3 % 3;
    int l  = r3 / 3;
    const float* src = (part == 0) ? wq : (part == 1) ? wk : wv;
    float v = src[(((size_t)l * 6 + h) * 384 + k) * 64 + e];
    Wt[((size_t)l * 1152 + part * 384 + h * 64 + e) * 384 + k] = f2bf(v);
}

// ---------------------------------------------------------------------------
// bf16 MFMA GEMM, 4 waves (256 thr), tile 128(M)x64(N), BK=64, single 24KB
// LDS buffer, m97 structure: stage -> vmcnt(0)+barrier -> MFMA -> barrier.
// 6 blocks/CU (24KB LDS); wave (wr=w>>1, wc=w&1) owns 64x32 -> 16 MFMA/K-step.
// C = A[M,K] @ Bt[N,K]^T (+bias)(+bf16 res)(ReLU); XCD swizzle (nwg%8==0).
// ---------------------------------------------------------------------------
__global__ __launch_bounds__(256, 6) void gemm128_k(
    const short* __restrict__ A,
    const short* __restrict__ Bt,
    const float* __restrict__ bias,
    const short* __restrict__ res16,
    float* __restrict__ out32,
    short* __restrict__ out16,
    int M, int K, int ldC, int Nmax, int relu) {
    __shared__ short As[128 * 64];   // 16 KB, 16 slots
    __shared__ short Bs[64 * 64];    // 8 KB, 8 slots
    const int t  = threadIdx.x;
    const int w  = t >> 6;
    const int l  = t & 63;

    // XCD-aware chunk swizzle (all grids have nwg % 8 == 0)
    const int gx  = gridDim.x;
    const int nwg = gx * gridDim.y;
    const int lin = blockIdx.y * gx + blockIdx.x;
    const int cpx = nwg >> 3;
    const int swz = (lin & 7) * cpx + (lin >> 3);
    const int m0 = (swz / gx) * 128;
    const int n0 = (swz % gx) * 64;

    const int wr = w >> 1, wc = w & 1;
    const int fr = l & 15, fq = l >> 4;

    // staging: A slots w*4+qi (qi 0..3), B slots w*2+qi (qi 0..1)
    // slot s covers rows s*8..s*8+7; lane -> row s*8+(l>>3), chunk (l&7)^(row&7)
    int arow[4], acol[4];
#pragma unroll
    for (int qi = 0; qi < 4; ++qi) {
        int r = (w * 4 + qi) * 8 + (l >> 3);
        arow[qi] = r;
        acol[qi] = (l & 7) ^ (r & 7);
    }
    int brow[2], bcol[2];
#pragma unroll
    for (int qi = 0; qi < 2; ++qi) {
        int r = (w * 2 + qi) * 8 + (l >> 3);
        brow[qi] = r;
        bcol[qi] = (l & 7) ^ (r & 7);
    }

    f32x4 acc[4][2];
#pragma unroll
    for (int i = 0; i < 4; ++i)
#pragma unroll
        for (int j = 0; j < 2; ++j) acc[i][j] = (f32x4)(0.0f);

    const int nt = K >> 6;

    for (int tk = 0; tk < nt; ++tk) {
        const int k0 = tk << 6;
#pragma unroll
        for (int qi = 0; qi < 4; ++qi)
            load_lds16(A + (size_t)(m0 + arow[qi]) * K + k0 + acol[qi] * 8,
                       (char*)As + (w * 4 + qi) * 1024);
#pragma unroll
        for (int qi = 0; qi < 2; ++qi)
            load_lds16(Bt + (size_t)(n0 + brow[qi]) * K + k0 + bcol[qi] * 8,
                       (char*)Bs + (w * 2 + qi) * 1024);
        asm volatile("s_waitcnt vmcnt(0)" ::: "memory");
        __syncthreads();   // tile fully staged

        __builtin_amdgcn_s_setprio(1);
#pragma unroll
        for (int ks = 0; ks < 2; ++ks) {
            const int kc = ks * 4 + fq;
            bf16x8 af[4], bfv[2];
#pragma unroll
            for (int mf = 0; mf < 4; ++mf) {
                int ar = wr * 64 + mf * 16 + fr;
                af[mf] = *reinterpret_cast<const bf16x8*>(
                    (const char*)As + ar * 128 + ((kc ^ (ar & 7)) << 4));
            }
#pragma unroll
            for (int nf = 0; nf < 2; ++nf) {
                int br = wc * 32 + nf * 16 + fr;
                bfv[nf] = *reinterpret_cast<const bf16x8*>(
                    (const char*)Bs + br * 128 + ((kc ^ (br & 7)) << 4));
            }
#pragma unroll
            for (int mf = 0; mf < 4; ++mf)
#pragma unroll
                for (int nf = 0; nf < 2; ++nf)
                    acc[mf][nf] = __builtin_amdgcn_mfma_f32_16x16x32_bf16(
                        af[mf], bfv[nf], acc[mf][nf], 0, 0, 0);
        }
        __builtin_amdgcn_s_setprio(0);
        __syncthreads();   // all waves done reading before next stage
    }

    // epilogue
#pragma unroll
    for (int mf = 0; mf < 4; ++mf) {
#pragma unroll
        for (int nf = 0; nf < 2; ++nf) {
            int n = n0 + wc * 32 + nf * 16 + fr;
            if (n < Nmax) {
#pragma unroll
                for (int j = 0; j < 4; ++j) {
                    int m = m0 + wr * 64 + mf * 16 + fq * 4 + j;
                    float v = acc[mf][nf][j];
                    if (bias)   v += bias[n];
                    if (res16)  v += bf2f(res16[(size_t)m * ldC + n]);
                    if (relu)   v = fmaxf(v, 0.f);
                    if (out32)  out32[(size_t)m * ldC + n] = v;
                    if (out16)  out16[(size_t)m * ldC + n] = f2bf(v);
                }
            }
        }
    }
}

// ---------------------------------------------------------------------------
// MFMA flash attention. Block per (h, b), 4 waves; wave w owns q-rows
// [w*64, w*64+64). qkv bf16 [BT][1152]: q at h*64, k at 384+h*64, v at 768+h*64.
// ---------------------------------------------------------------------------
__global__ __launch_bounds__(256) void attn_mfma_k(const short* __restrict__ qkv,
                                                   short* __restrict__ o) {
    __shared__ short Vt[16384];        // [64 d][256 k], byte = d*512 + k*2 ^ ((d&7)<<4)
    __shared__ short Pw[4][4096];      // per wave [64 q][64 k], byte = q*128 + k*2 ^ ((q&7)<<4)

    const int hh = blockIdx.x;
    const int bb = blockIdx.y;
    const int t  = threadIdx.x;
    const int w  = t >> 6;
    const int lane = t & 63;
    const int fr = lane & 15, fq = lane >> 4;
    const int bt0 = bb * TT;

    // ---- stage V^T (transposed, XOR-swizzled) ----
    {
        const int r0 = (t & 127) * 2;
        const int dbase = (t >> 7) * 32;
        const short* v0 = qkv + (size_t)(bt0 + r0) * 1152 + 768 + hh * 64 + dbase;
        short a0[32], a1[32];
#pragma unroll
        for (int i = 0; i < 4; ++i) {
            *(bf16x8*)(a0 + i * 8) = *(const bf16x8*)(v0 + i * 8);
            *(bf16x8*)(a1 + i * 8) = *(const bf16x8*)(v0 + 1152 + i * 8);
        }
#pragma unroll
        for (int i = 0; i < 32; ++i) {
            int d = dbase + i;
            int byte = (d * 512 + r0 * 2) ^ ((d & 7) << 4);
            unsigned int pk = (unsigned int)(unsigned short)a0[i] |
                              ((unsigned int)(unsigned short)a1[i] << 16);
            *(unsigned int*)((char*)Vt + byte) = pk;
        }
    }
    __syncthreads();

    char* PwW = (char*)Pw[w];

    bf16x8 qb[4][2];
#pragma unroll
    for (int nf = 0; nf < 4; ++nf)
#pragma unroll
        for (int ks = 0; ks < 2; ++ks)
            qb[nf][ks] = *(const bf16x8*)(qkv + (size_t)(bt0 + w * 64 + nf * 16 + fr) * 1152 +
                                          hh * 64 + ks * 32 + fq * 8);

    f32x4 o_acc[4][4];
#pragma unroll
    for (int i = 0; i < 4; ++i)
#pragma unroll
        for (int j = 0; j < 4; ++j) o_acc[i][j] = (f32x4)(0.0f);
    float m_run[4], l_run[4];
#pragma unroll
    for (int nf = 0; nf < 4; ++nf) { m_run[nf] = -1e30f; l_run[nf] = 0.f; }

    for (int kt = 0; kt <= w; ++kt) {
        bf16x8 ak[4][2];
#pragma unroll
        for (int mf = 0; mf < 4; ++mf)
#pragma unroll
            for (int ks = 0; ks < 2; ++ks)
                ak[mf][ks] = *(const bf16x8*)(qkv + (size_t)(bt0 + kt * 64 + mf * 16 + fr) * 1152 +
                                              384 + hh * 64 + ks * 32 + fq * 8);

        f32x4 s[4][4];
#pragma unroll
        for (int i = 0; i < 4; ++i)
#pragma unroll
            for (int j = 0; j < 4; ++j) s[i][j] = (f32x4)(0.0f);
#pragma unroll
        for (int ks = 0; ks < 2; ++ks)
#pragma unroll
            for (int mf = 0; mf < 4; ++mf)
#pragma unroll
                for (int nf = 0; nf < 4; ++nf)
                    s[mf][nf] = __builtin_amdgcn_mfma_f32_16x16x32_bf16(
                        ak[mf][ks], qb[nf][ks], s[mf][nf], 0, 0, 0);

        const bool diag = (kt == w);
#pragma unroll
        for (int mf = 0; mf < 4; ++mf)
#pragma unroll
            for (int nf = 0; nf < 4; ++nf)
#pragma unroll
                for (int j = 0; j < 4; ++j) {
                    float v = s[mf][nf][j] * SCALE;
                    if (diag && (mf * 16 + fq * 4 + j > nf * 16 + fr)) v = -1e30f;
                    s[mf][nf][j] = v;
                }

        float fac[4];
#pragma unroll
        for (int nf = 0; nf < 4; ++nf) {
            float mx = -1e30f;
#pragma unroll
            for (int mf = 0; mf < 4; ++mf)
#pragma unroll
                for (int j = 0; j < 4; ++j) mx = fmaxf(mx, s[mf][nf][j]);
            mx = fmaxf(mx, __shfl_xor(mx, 16));
            mx = fmaxf(mx, __shfl_xor(mx, 32));
            float mnew = fmaxf(m_run[nf], mx);
            fac[nf] = __expf(m_run[nf] - mnew);
            m_run[nf] = mnew;
        }

#pragma unroll
        for (int nf = 0; nf < 4; ++nf) {
            float ps = 0.f;
#pragma unroll
            for (int mf = 0; mf < 4; ++mf)
#pragma unroll
                for (int j = 0; j < 4; ++j) {
                    float p = __expf(s[mf][nf][j] - m_run[nf]);
                    s[mf][nf][j] = p;
                    ps += p;
                }
            ps += __shfl_xor(ps, 16);
            ps += __shfl_xor(ps, 32);
            l_run[nf] = l_run[nf] * fac[nf] + ps;
        }

#pragma unroll
        for (int mf = 0; mf < 4; ++mf)
#pragma unroll
            for (int nf = 0; nf < 4; ++nf) {
                unsigned long long pk =
                    (unsigned long long)(unsigned short)f2bf(s[mf][nf][0]) |
                    ((unsigned long long)(unsigned short)f2bf(s[mf][nf][1]) << 16) |
                    ((unsigned long long)(unsigned short)f2bf(s[mf][nf][2]) << 32) |
                    ((unsigned long long)(unsigned short)f2bf(s[mf][nf][3]) << 48);
                int q = nf * 16 + fr;
                int byte = (q * 128 + mf * 32 + fq * 8) ^ ((q & 7) << 4);
                *(unsigned long long*)(PwW + byte) = pk;
            }

#pragma unroll
        for (int j = 0; j < 4; ++j) {
            int src = (lane & 48) + ((lane & 48) >> 2) + j;
#pragma unroll
            for (int mo = 0; mo < 4; ++mo) {
                float f = __shfl(fac[mo], src);
#pragma unroll
                for (int df = 0; df < 4; ++df) o_acc[mo][df][j] *= f;
            }
        }

        bf16x8 ap[4][2], bv[4][2];
#pragma unroll
        for (int mo = 0; mo < 4; ++mo)
#pragma unroll
            for (int ks = 0; ks < 2; ++ks) {
                int byte = ((mo * 16 + fr) * 128 + ks * 64 + fq * 16) ^ ((fr & 7) << 4);
                ap[mo][ks] = *(const bf16x8*)(PwW + byte);
            }
#pragma unroll
        for (int df = 0; df < 4; ++df)
#pragma unroll
            for (int ks = 0; ks < 2; ++ks) {
                int byte = ((df * 16 + fr) * 512 + kt * 128 + ks * 64 + fq * 16) ^ ((fr & 7) << 4);
                bv[df][ks] = *(const bf16x8*)((const char*)Vt + byte);
            }
#pragma unroll
        for (int ks = 0; ks < 2; ++ks)
#pragma unroll
            for (int mo = 0; mo < 4; ++mo)
#pragma unroll
                for (int df = 0; df < 4; ++df)
                    o_acc[mo][df] = __builtin_amdgcn_mfma_f32_16x16x32_bf16(
                        ap[mo][ks], bv[df][ks], o_acc[mo][df], 0, 0, 0);
    }

    float linv[4];
#pragma unroll
    for (int nf = 0; nf < 4; ++nf) linv[nf] = 1.0f / l_run[nf];
#pragma unroll
    for (int j = 0; j < 4; ++j) {
        int src = (lane & 48) + ((lane & 48) >> 2) + j;
#pragma unroll
        for (int mo = 0; mo < 4; ++mo) {
            float li = __shfl(linv[mo], src);
#pragma unroll
            for (int df = 0; df < 4; ++df) {
                float val = o_acc[mo][df][j] * li;
                o[(size_t)(bt0 + w * 64 + mo * 16 + fq * 4 + j) * DD + hh * 64 + df * 16 + fr] =
                    f2bf(val);
            }
        }
    }
}

// ---------------------------------------------------------------------------
// Host orchestration
// ---------------------------------------------------------------------------
extern "C" void kernel_launch(void* const* d_in, const int* in_sizes, int n_in,
                              void* d_out, int out_size, void* d_ws, size_t ws_size,
                              hipStream_t stream) {
    const int*   idx     = (const int*)d_in[0];
    const float* tok_emb = (const float*)d_in[1];
    const float* pos_emb = (const float*)d_in[2];
    const float* ln1_w   = (const float*)d_in[3];
    const float* ln1_b   = (const float*)d_in[4];
    const float* wq      = (const float*)d_in[5];
    const float* wk      = (const float*)d_in[6];
    const float* wv      = (const float*)d_in[7];
    const float* proj_w  = (const float*)d_in[8];
    const float* proj_b  = (const float*)d_in[9];
    const float* ln2_w   = (const float*)d_in[10];
    const float* ln2_b   = (const float*)d_in[11];
    const float* ff_w1   = (const float*)d_in[12];
    const float* ff_b1   = (const float*)d_in[13];
    const float* ff_w2   = (const float*)d_in[14];
    const float* ff_b2   = (const float*)d_in[15];
    const float* lnf_w   = (const float*)d_in[16];
    const float* lnf_b   = (const float*)d_in[17];
    const float* head_w  = (const float*)d_in[18];
    const float* head_b  = (const float*)d_in[19];
    float* out = (float*)d_out;

    // workspace carve-up
    char* p = (char*)d_ws;
    short* x16    = (short*)p;  p += (size_t)BT * DD * 2;        // 12.6 MB
    short* qkv16  = (short*)p;  p += (size_t)BT * 1152 * 2;      // 37.7 MB
    short* h16    = (short*)p;  p += (size_t)BT * DD * 2;        // 12.6 MB
    short* o16    = (short*)p;  p += (size_t)BT * DD * 2;        // 12.6 MB
    short* ff16   = (short*)p;  p += (size_t)BT * FFD * 2;       // 50.3 MB
    short* wqkvT  = (short*)p;  p += (size_t)LL * 1152 * 384 * 2;
    short* projT  = (short*)p;  p += (size_t)LL * 384 * 384 * 2;
    short* ff1T   = (short*)p;  p += (size_t)LL * 1536 * 384 * 2;
    short* ff2T   = (short*)p;  p += (size_t)LL * 384 * 1536 * 2;
    short* headT  = (short*)p;  p += (size_t)128 * 384 * 2;

    const dim3 blk(256);

    qkvconv_k<<<dim3(2654208 / 256), blk, 0, stream>>>(wq, wk, wv, wqkvT);
    wconv_k<<<dim3(12, 12, 6), blk, 0, stream>>>(proj_w, projT, 384, 384, 384);
    wconv_k<<<dim3(48, 12, 6), blk, 0, stream>>>(ff_w1, ff1T, 384, 1536, 1536);
    wconv_k<<<dim3(12, 48, 6), blk, 0, stream>>>(ff_w2, ff2T, 1536, 384, 384);
    wconv_k<<<dim3(4, 12, 1), blk, 0, stream>>>(head_w, headT, 384, 65, 128);

    embed_k<<<dim3((BT * 48) / 256), blk, 0, stream>>>(idx, tok_emb, pos_emb, x16);

    const dim3 gLN(BT / 4);
    const dim3 gAttn(HH, BB);
    const dim3 gQKV(1152 / 64, BT / 128);   // 18 x 128 = 2304 blocks
    const dim3 gD(384 / 64, BT / 128);      // 6 x 128 = 768 blocks
    const dim3 gFF(1536 / 64, BT / 128);    // 24 x 128 = 3072 blocks
    const dim3 gHead(128 / 64, BT / 128);   // 2 x 128 = 256 blocks

    for (int l = 0; l < LL; ++l) {
        const size_t dOff = (size_t)l * DD;

        ln_k<<<gLN, blk, 0, stream>>>(x16, ln1_w + dOff, ln1_b + dOff, h16);

        // qkv16 = h @ Wqkv (bf16 out)
        gemm128_k<<<gQKV, blk, 0, stream>>>(h16, wqkvT + (size_t)l * 1152 * 384,
                                            nullptr, nullptr, nullptr, qkv16,
                                            BT, 384, 1152, 1152, 0);

        attn_mfma_k<<<gAttn, blk, 0, stream>>>(qkv16, o16);

        // x = x + o @ proj_w + proj_b   (bf16 residual stream)
        gemm128_k<<<gD, blk, 0, stream>>>(o16, projT + (size_t)l * 384 * 384,
                                          proj_b + dOff, x16, nullptr, x16,
                                          BT, 384, 384, 384, 0);

        ln_k<<<gLN, blk, 0, stream>>>(x16, ln2_w + dOff, ln2_b + dOff, h16);

        // ff = relu(h @ W1 + b1) (bf16 out)
        gemm128_k<<<gFF, blk, 0, stream>>>(h16, ff1T + (size_t)l * 1536 * 384,
                                           ff_b1 + (size_t)l * FFD, nullptr,
                                           nullptr, ff16,
                                           BT, 384, 1536, 1536, 1);

        // x = x + ff @ W2 + b2
        gemm128_k<<<gD, blk, 0, stream>>>(ff16, ff2T + (size_t)l * 384 * 1536,
                                          ff_b2 + dOff, x16, nullptr, x16,
                                          BT, 1536, 384, 384, 0);
    }

    ln_k<<<gLN, blk, 0, stream>>>(x16, lnf_w, lnf_b, h16);
    gemm128_k<<<gHead, blk, 0, stream>>>(h16, headT, head_b, nullptr, out, nullptr,
                                         BT, 384, 65, 65, 0);
}

// Round 9
// 1167.967 us; speedup vs baseline: 1.1021x; 1.1021x over previous
//
#include <hip/hip_runtime.h>
#include <hip/hip_bf16.h>
#include <math.h>

// Problem constants
#define BB   64
#define TT   256
#define VV   65
#define DD   384
#define HH   6
#define HDD  64
#define LL   6
#define FFD  1536
#define BT   (BB * TT)        // 16384 rows
#define EPSL 1e-5f
#define SCALE 0.05103103630798287f  // 384^-0.5

using bf16x8 = __attribute__((ext_vector_type(8))) short;
using f32x4  = __attribute__((ext_vector_type(4))) float;

__device__ __forceinline__ short f2bf(float f) {
    __hip_bfloat16 h = __float2bfloat16(f);
    return *reinterpret_cast<short*>(&h);
}
__device__ __forceinline__ float bf2f(short s) {
    union { unsigned u; float f; } c;
    c.u = ((unsigned)(unsigned short)s) << 16;
    return c.f;
}

__device__ __forceinline__ void load_lds16(const void* g, void* lds_base) {
    __builtin_amdgcn_global_load_lds(
        (const __attribute__((address_space(1))) void*)g,
        (__attribute__((address_space(3))) void*)lds_base,
        16, 0, 0);
}

// ---------------------------------------------------------------------------
// Embedding -> bf16 x
// ---------------------------------------------------------------------------
__global__ __launch_bounds__(256) void embed_k(const int* __restrict__ idx,
                                               const float* __restrict__ tok,
                                               const float* __restrict__ pos,
                                               short* __restrict__ x) {
    int i = blockIdx.x * 256 + threadIdx.x;     // BT*48 threads
    int bt = i / 48;
    int g  = i - bt * 48;
    int t  = bt & (TT - 1);
    const float4* tp = (const float4*)tok + (size_t)idx[bt] * 96 + g * 2;
    const float4* pp = (const float4*)pos + (size_t)t * 96 + g * 2;
    float4 a0 = tp[0], a1 = tp[1], p0 = pp[0], p1 = pp[1];
    bf16x8 o;
    o[0] = f2bf(a0.x + p0.x); o[1] = f2bf(a0.y + p0.y);
    o[2] = f2bf(a0.z + p0.z); o[3] = f2bf(a0.w + p0.w);
    o[4] = f2bf(a1.x + p1.x); o[5] = f2bf(a1.y + p1.y);
    o[6] = f2bf(a1.z + p1.z); o[7] = f2bf(a1.w + p1.w);
    *reinterpret_cast<bf16x8*>(x + (size_t)bt * DD + g * 8) = o;
}

// ---------------------------------------------------------------------------
// LayerNorm bf16 in -> bf16 out. One wave per row; block = 4 rows.
// ---------------------------------------------------------------------------
__global__ __launch_bounds__(256) void ln_k(const short* __restrict__ in,
                                            const float* __restrict__ w,
                                            const float* __restrict__ b,
                                            short* __restrict__ out) {
    int row  = blockIdx.x * 4 + (threadIdx.x >> 6);
    int lane = threadIdx.x & 63;
    const unsigned* pu = (const unsigned*)(in + (size_t)row * DD);
    unsigned u0 = pu[lane], u1 = pu[lane + 64], u2 = pu[lane + 128];
    float v00 = bf2f((short)(u0 & 0xffff)), v01 = bf2f((short)(u0 >> 16));
    float v10 = bf2f((short)(u1 & 0xffff)), v11 = bf2f((short)(u1 >> 16));
    float v20 = bf2f((short)(u2 & 0xffff)), v21 = bf2f((short)(u2 >> 16));
    float s = v00 + v01 + v10 + v11 + v20 + v21;
#pragma unroll
    for (int off = 32; off; off >>= 1) s += __shfl_xor(s, off);
    float mean = s * (1.0f / DD);
    float d00 = v00 - mean, d01 = v01 - mean, d10 = v10 - mean,
          d11 = v11 - mean, d20 = v20 - mean, d21 = v21 - mean;
    float s2 = d00*d00 + d01*d01 + d10*d10 + d11*d11 + d20*d20 + d21*d21;
#pragma unroll
    for (int off = 32; off; off >>= 1) s2 += __shfl_xor(s2, off);
    float rstd = rsqrtf(s2 * (1.0f / DD) + EPSL);
    int c0 = lane * 2, c1 = c0 + 128, c2 = c0 + 256;
    unsigned* po = (unsigned*)(out + (size_t)row * DD);
    unsigned r0 = (unsigned)(unsigned short)f2bf(d00 * rstd * w[c0] + b[c0]) |
                  ((unsigned)(unsigned short)f2bf(d01 * rstd * w[c0+1] + b[c0+1]) << 16);
    unsigned r1 = (unsigned)(unsigned short)f2bf(d10 * rstd * w[c1] + b[c1]) |
                  ((unsigned)(unsigned short)f2bf(d11 * rstd * w[c1+1] + b[c1+1]) << 16);
    unsigned r2 = (unsigned)(unsigned short)f2bf(d20 * rstd * w[c2] + b[c2]) |
                  ((unsigned)(unsigned short)f2bf(d21 * rstd * w[c2+1] + b[c2+1]) << 16);
    po[lane] = r0; po[lane + 64] = r1; po[lane + 128] = r2;
}

// ---------------------------------------------------------------------------
// Weight transpose+convert: W[K][N] f32 -> Wt[Npad][K] bf16
// ---------------------------------------------------------------------------
__global__ __launch_bounds__(256) void wconv_k(const float* __restrict__ W,
                                               short* __restrict__ Wt,
                                               int K, int N, int Npad) {
    __shared__ float tile[32][33];
    W  += (size_t)blockIdx.z * K * N;
    Wt += (size_t)blockIdx.z * Npad * K;
    const int t  = threadIdx.x;
    const int c  = t & 31;
    const int r8 = t >> 5;
    const int k0 = blockIdx.y * 32;
    const int n0 = blockIdx.x * 32;
#pragma unroll
    for (int p = 0; p < 4; ++p) {
        int kk = r8 + 8 * p;
        int n  = n0 + c;
        tile[kk][c] = (n < N) ? W[(size_t)(k0 + kk) * N + n] : 0.f;
    }
    __syncthreads();
#pragma unroll
    for (int p = 0; p < 4; ++p) {
        int nl = r8 + 8 * p;
        Wt[(size_t)(n0 + nl) * K + k0 + c] = f2bf(tile[c][nl]);
    }
}

// ---------------------------------------------------------------------------
// QKV weight convert -> WqkvT [L][1152][384] bf16
// ---------------------------------------------------------------------------
__global__ __launch_bounds__(256) void qkvconv_k(const float* __restrict__ wq,
                                                 const float* __restrict__ wk,
                                                 const float* __restrict__ wv,
                                                 short* __restrict__ Wt) {
    int tid = blockIdx.x * 256 + threadIdx.x;
    int e  = tid & 63;
    int k  = (tid >> 6) % 384;
    int r2 = (tid >> 6) / 384;
    int h  = r2 % 6;
    int r3 = r2 / 6;
    int part = r3 % 3;
    int l  = r3 / 3;
    const float* src = (part == 0) ? wq : (part == 1) ? wk : wv;
    float v = src[(((size_t)l * 6 + h) * 384 + k) * 64 + e];
    Wt[((size_t)l * 1152 + part * 384 + h * 64 + e) * 384 + k] = f2bf(v);
}

// ---------------------------------------------------------------------------
// bf16 MFMA GEMM (round-7 validated geometry): 4 waves (256 thr), tile 64x64,
// BK=64, single 16KB LDS buffer, m97 structure. 8 blocks/CU -> block-level
// TLP hides the per-iter drain. bf16 residual supported in epilogue.
// C = A[M,K] @ Bt[N,K]^T (+bias)(+res16)(ReLU); XCD swizzle (nwg%8==0).
// ---------------------------------------------------------------------------
__global__ __launch_bounds__(256, 8) void gemm64_k(
    const short* __restrict__ A,
    const short* __restrict__ Bt,
    const float* __restrict__ bias,
    const short* __restrict__ res16,
    float* __restrict__ out32,
    short* __restrict__ out16,
    int M, int K, int ldC, int Nmax, int relu) {
    __shared__ short As[4096];   // 64 rows x 64 k
    __shared__ short Bs[4096];
    const int t  = threadIdx.x;
    const int w  = t >> 6;
    const int l  = t & 63;

    const int gx  = gridDim.x;
    const int nwg = gx * gridDim.y;
    const int lin = blockIdx.y * gx + blockIdx.x;
    const int cpx = nwg >> 3;
    const int swz = (lin & 7) * cpx + (lin >> 3);
    const int m0 = (swz / gx) * 64;
    const int n0 = (swz % gx) * 64;

    const int wr = w >> 1, wc = w & 1;
    const int fr = l & 15, fq = l >> 4;

    int srow[2], scol[2];
#pragma unroll
    for (int qi = 0; qi < 2; ++qi) {
        int s = w * 2 + qi;
        int r = s * 8 + (l >> 3);
        int c = l & 7;
        srow[qi] = r;
        scol[qi] = c ^ (r & 7);
    }

    f32x4 acc[2][2];
#pragma unroll
    for (int i = 0; i < 2; ++i)
#pragma unroll
        for (int j = 0; j < 2; ++j) acc[i][j] = (f32x4)(0.0f);

    const int nt = K >> 6;

    for (int tk = 0; tk < nt; ++tk) {
        const int k0 = tk << 6;
#pragma unroll
        for (int qi = 0; qi < 2; ++qi)
            load_lds16(A + (size_t)(m0 + srow[qi]) * K + k0 + scol[qi] * 8,
                       (char*)As + (w * 2 + qi) * 1024);
#pragma unroll
        for (int qi = 0; qi < 2; ++qi)
            load_lds16(Bt + (size_t)(n0 + srow[qi]) * K + k0 + scol[qi] * 8,
                       (char*)Bs + (w * 2 + qi) * 1024);
        asm volatile("s_waitcnt vmcnt(0)" ::: "memory");
        __syncthreads();

        __builtin_amdgcn_s_setprio(1);
#pragma unroll
        for (int ks = 0; ks < 2; ++ks) {
            const int kc = ks * 4 + fq;
            bf16x8 af[2], bfv[2];
#pragma unroll
            for (int mf = 0; mf < 2; ++mf) {
                int ar = wr * 32 + mf * 16 + fr;
                af[mf] = *reinterpret_cast<const bf16x8*>(
                    (const char*)As + ar * 128 + ((kc ^ (ar & 7)) << 4));
            }
#pragma unroll
            for (int nf = 0; nf < 2; ++nf) {
                int br = wc * 32 + nf * 16 + fr;
                bfv[nf] = *reinterpret_cast<const bf16x8*>(
                    (const char*)Bs + br * 128 + ((kc ^ (br & 7)) << 4));
            }
#pragma unroll
            for (int mf = 0; mf < 2; ++mf)
#pragma unroll
                for (int nf = 0; nf < 2; ++nf)
                    acc[mf][nf] = __builtin_amdgcn_mfma_f32_16x16x32_bf16(
                        af[mf], bfv[nf], acc[mf][nf], 0, 0, 0);
        }
        __builtin_amdgcn_s_setprio(0);
        __syncthreads();
    }

#pragma unroll
    for (int mf = 0; mf < 2; ++mf) {
#pragma unroll
        for (int nf = 0; nf < 2; ++nf) {
            int n = n0 + wc * 32 + nf * 16 + fr;
            if (n < Nmax) {
#pragma unroll
                for (int j = 0; j < 4; ++j) {
                    int m = m0 + wr * 32 + mf * 16 + fq * 4 + j;
                    float v = acc[mf][nf][j];
                    if (bias)   v += bias[n];
                    if (res16)  v += bf2f(res16[(size_t)m * ldC + n]);
                    if (relu)   v = fmaxf(v, 0.f);
                    if (out32)  out32[(size_t)m * ldC + n] = v;
                    if (out16)  out16[(size_t)m * ldC + n] = f2bf(v);
                }
            }
        }
    }
}

// ---------------------------------------------------------------------------
// MFMA flash attention, causal-BALANCED. Block per (h, b), 4 waves.
// Wave w owns TWO 32-row q-tiles: qt=w and qt=7-w -> uniform 5 k-tile units
// per wave (vs 1..4 skewed before). Groups processed sequentially; group A's
// output is written before group B starts (caps VGPR).
// qkv bf16 [BT][1152]: q at h*64, k at 384+h*64, v at 768+h*64.
// LDS: Vt 32KB + 4x4KB P = 48KB -> 3 blocks/CU.
// ---------------------------------------------------------------------------
__global__ __launch_bounds__(256) void attn_mfma_k(const short* __restrict__ qkv,
                                                   short* __restrict__ o) {
    __shared__ short Vt[16384];        // [64 d][256 k], byte = d*512+k*2 ^ ((d&7)<<4)
    __shared__ short Pw[4][2048];      // per wave [32 q][64 k], byte = q*128+k*2 ^ ((q&7)<<4)

    const int hh = blockIdx.x;
    const int bb = blockIdx.y;
    const int t  = threadIdx.x;
    const int w  = t >> 6;
    const int lane = t & 63;
    const int fr = lane & 15, fq = lane >> 4;
    const int bt0 = bb * TT;

    // ---- stage V^T (transposed, XOR-swizzled) ----
    {
        const int r0 = (t & 127) * 2;
        const int dbase = (t >> 7) * 32;
        const short* v0 = qkv + (size_t)(bt0 + r0) * 1152 + 768 + hh * 64 + dbase;
        short a0[32], a1[32];
#pragma unroll
        for (int i = 0; i < 4; ++i) {
            *(bf16x8*)(a0 + i * 8) = *(const bf16x8*)(v0 + i * 8);
            *(bf16x8*)(a1 + i * 8) = *(const bf16x8*)(v0 + 1152 + i * 8);
        }
#pragma unroll
        for (int i = 0; i < 32; ++i) {
            int d = dbase + i;
            int byte = (d * 512 + r0 * 2) ^ ((d & 7) << 4);
            unsigned int pk = (unsigned int)(unsigned short)a0[i] |
                              ((unsigned int)(unsigned short)a1[i] << 16);
            *(unsigned int*)((char*)Vt + byte) = pk;
        }
    }
    __syncthreads();

    char* PwW = (char*)Pw[w];

#pragma unroll
    for (int grp = 0; grp < 2; ++grp) {
        const int qt = grp ? (7 - w) : w;
        const int q0 = qt * 32;
        const int ktm = qt >> 1;

        // Q B-frags for this 32-row tile
        bf16x8 qb[2][2];
#pragma unroll
        for (int nf = 0; nf < 2; ++nf)
#pragma unroll
            for (int ks = 0; ks < 2; ++ks)
                qb[nf][ks] = *(const bf16x8*)(qkv + (size_t)(bt0 + q0 + nf * 16 + fr) * 1152 +
                                              hh * 64 + ks * 32 + fq * 8);

        f32x4 o_acc[2][4];
#pragma unroll
        for (int i = 0; i < 2; ++i)
#pragma unroll
            for (int j = 0; j < 4; ++j) o_acc[i][j] = (f32x4)(0.0f);
        float m_run[2] = {-1e30f, -1e30f};
        float l_run[2] = {0.f, 0.f};

        for (int kt = 0; kt <= ktm; ++kt) {
            // K A-frags: rows k = kt*64 + mf*16 + fr
            bf16x8 ak[4][2];
#pragma unroll
            for (int mf = 0; mf < 4; ++mf)
#pragma unroll
                for (int ks = 0; ks < 2; ++ks)
                    ak[mf][ks] = *(const bf16x8*)(qkv +
                        (size_t)(bt0 + kt * 64 + mf * 16 + fr) * 1152 +
                        384 + hh * 64 + ks * 32 + fq * 8);

            // S^T = K @ Q^T : reg (mf,j) = k row, col = q (nf*16+fr)
            f32x4 s[4][2];
#pragma unroll
            for (int i = 0; i < 4; ++i)
#pragma unroll
                for (int j = 0; j < 2; ++j) s[i][j] = (f32x4)(0.0f);
#pragma unroll
            for (int ks = 0; ks < 2; ++ks)
#pragma unroll
                for (int mf = 0; mf < 4; ++mf)
#pragma unroll
                    for (int nf = 0; nf < 2; ++nf)
                        s[mf][nf] = __builtin_amdgcn_mfma_f32_16x16x32_bf16(
                            ak[mf][ks], qb[nf][ks], s[mf][nf], 0, 0, 0);

            const bool diag = (kt == ktm);
#pragma unroll
            for (int mf = 0; mf < 4; ++mf)
#pragma unroll
                for (int nf = 0; nf < 2; ++nf)
#pragma unroll
                    for (int j = 0; j < 4; ++j) {
                        float v = s[mf][nf][j] * SCALE;
                        if (diag && (kt * 64 + mf * 16 + fq * 4 + j >
                                     q0 + nf * 16 + fr)) v = -1e30f;
                        s[mf][nf][j] = v;
                    }

            float fac[2];
#pragma unroll
            for (int nf = 0; nf < 2; ++nf) {
                float mx = -1e30f;
#pragma unroll
                for (int mf = 0; mf < 4; ++mf)
#pragma unroll
                    for (int j = 0; j < 4; ++j) mx = fmaxf(mx, s[mf][nf][j]);
                mx = fmaxf(mx, __shfl_xor(mx, 16));
                mx = fmaxf(mx, __shfl_xor(mx, 32));
                float mnew = fmaxf(m_run[nf], mx);
                fac[nf] = __expf(m_run[nf] - mnew);
                m_run[nf] = mnew;
            }

#pragma unroll
            for (int nf = 0; nf < 2; ++nf) {
                float ps = 0.f;
#pragma unroll
                for (int mf = 0; mf < 4; ++mf)
#pragma unroll
                    for (int j = 0; j < 4; ++j) {
                        float p = __expf(s[mf][nf][j] - m_run[nf]);
                        s[mf][nf][j] = p;
                        ps += p;
                    }
                ps += __shfl_xor(ps, 16);
                ps += __shfl_xor(ps, 32);
                l_run[nf] = l_run[nf] * fac[nf] + ps;
            }

            // P (bf16) -> wave-private LDS [32 q][64 k]
#pragma unroll
            for (int mf = 0; mf < 4; ++mf)
#pragma unroll
                for (int nf = 0; nf < 2; ++nf) {
                    unsigned long long pk =
                        (unsigned long long)(unsigned short)f2bf(s[mf][nf][0]) |
                        ((unsigned long long)(unsigned short)f2bf(s[mf][nf][1]) << 16) |
                        ((unsigned long long)(unsigned short)f2bf(s[mf][nf][2]) << 32) |
                        ((unsigned long long)(unsigned short)f2bf(s[mf][nf][3]) << 48);
                    int q = nf * 16 + fr;
                    int byte = (q * 128 + mf * 32 + fq * 8) ^ ((q & 7) << 4);
                    *(unsigned long long*)(PwW + byte) = pk;
                }

            // rescale O by fac (broadcast per q-row)
#pragma unroll
            for (int j = 0; j < 4; ++j) {
                int src = (lane & 48) + ((lane & 48) >> 2) + j;
#pragma unroll
                for (int mo = 0; mo < 2; ++mo) {
                    float f = __shfl(fac[mo], src);
#pragma unroll
                    for (int df = 0; df < 4; ++df) o_acc[mo][df][j] *= f;
                }
            }

            // O += P @ V
            bf16x8 ap[2][2], bv[4][2];
#pragma unroll
            for (int mo = 0; mo < 2; ++mo)
#pragma unroll
                for (int ks = 0; ks < 2; ++ks) {
                    int byte = ((mo * 16 + fr) * 128 + ks * 64 + fq * 16) ^ ((fr & 7) << 4);
                    ap[mo][ks] = *(const bf16x8*)(PwW + byte);
                }
#pragma unroll
            for (int df = 0; df < 4; ++df)
#pragma unroll
                for (int ks = 0; ks < 2; ++ks) {
                    int byte = ((df * 16 + fr) * 512 + kt * 128 + ks * 64 + fq * 16) ^
                               ((fr & 7) << 4);
                    bv[df][ks] = *(const bf16x8*)((const char*)Vt + byte);
                }
#pragma unroll
            for (int ks = 0; ks < 2; ++ks)
#pragma unroll
                for (int mo = 0; mo < 2; ++mo)
#pragma unroll
                    for (int df = 0; df < 4; ++df)
                        o_acc[mo][df] = __builtin_amdgcn_mfma_f32_16x16x32_bf16(
                            ap[mo][ks], bv[df][ks], o_acc[mo][df], 0, 0, 0);
        }

        // epilogue for this group: O /= l, write bf16
        float linv[2];
#pragma unroll
        for (int nf = 0; nf < 2; ++nf) linv[nf] = 1.0f / l_run[nf];
#pragma unroll
        for (int j = 0; j < 4; ++j) {
            int src = (lane & 48) + ((lane & 48) >> 2) + j;
#pragma unroll
            for (int mo = 0; mo < 2; ++mo) {
                float li = __shfl(linv[mo], src);
#pragma unroll
                for (int df = 0; df < 4; ++df) {
                    float val = o_acc[mo][df][j] * li;
                    o[(size_t)(bt0 + q0 + mo * 16 + fq * 4 + j) * DD +
                      hh * 64 + df * 16 + fr] = f2bf(val);
                }
            }
        }
    }
}

// ---------------------------------------------------------------------------
// Host orchestration
// ---------------------------------------------------------------------------
extern "C" void kernel_launch(void* const* d_in, const int* in_sizes, int n_in,
                              void* d_out, int out_size, void* d_ws, size_t ws_size,
                              hipStream_t stream) {
    const int*   idx     = (const int*)d_in[0];
    const float* tok_emb = (const float*)d_in[1];
    const float* pos_emb = (const float*)d_in[2];
    const float* ln1_w   = (const float*)d_in[3];
    const float* ln1_b   = (const float*)d_in[4];
    const float* wq      = (const float*)d_in[5];
    const float* wk      = (const float*)d_in[6];
    const float* wv      = (const float*)d_in[7];
    const float* proj_w  = (const float*)d_in[8];
    const float* proj_b  = (const float*)d_in[9];
    const float* ln2_w   = (const float*)d_in[10];
    const float* ln2_b   = (const float*)d_in[11];
    const float* ff_w1   = (const float*)d_in[12];
    const float* ff_b1   = (const float*)d_in[13];
    const float* ff_w2   = (const float*)d_in[14];
    const float* ff_b2   = (const float*)d_in[15];
    const float* lnf_w   = (const float*)d_in[16];
    const float* lnf_b   = (const float*)d_in[17];
    const float* head_w  = (const float*)d_in[18];
    const float* head_b  = (const float*)d_in[19];
    float* out = (float*)d_out;

    // workspace carve-up
    char* p = (char*)d_ws;
    short* x16    = (short*)p;  p += (size_t)BT * DD * 2;        // 12.6 MB
    short* qkv16  = (short*)p;  p += (size_t)BT * 1152 * 2;      // 37.7 MB
    short* h16    = (short*)p;  p += (size_t)BT * DD * 2;        // 12.6 MB
    short* o16    = (short*)p;  p += (size_t)BT * DD * 2;        // 12.6 MB
    short* ff16   = (short*)p;  p += (size_t)BT * FFD * 2;       // 50.3 MB
    short* wqkvT  = (short*)p;  p += (size_t)LL * 1152 * 384 * 2;
    short* projT  = (short*)p;  p += (size_t)LL * 384 * 384 * 2;
    short* ff1T   = (short*)p;  p += (size_t)LL * 1536 * 384 * 2;
    short* ff2T   = (short*)p;  p += (size_t)LL * 384 * 1536 * 2;
    short* headT  = (short*)p;  p += (size_t)128 * 384 * 2;

    const dim3 blk(256);

    qkvconv_k<<<dim3(2654208 / 256), blk, 0, stream>>>(wq, wk, wv, wqkvT);
    wconv_k<<<dim3(12, 12, 6), blk, 0, stream>>>(proj_w, projT, 384, 384, 384);
    wconv_k<<<dim3(48, 12, 6), blk, 0, stream>>>(ff_w1, ff1T, 384, 1536, 1536);
    wconv_k<<<dim3(12, 48, 6), blk, 0, stream>>>(ff_w2, ff2T, 1536, 384, 384);
    wconv_k<<<dim3(4, 12, 1), blk, 0, stream>>>(head_w, headT, 384, 65, 128);

    embed_k<<<dim3((BT * 48) / 256), blk, 0, stream>>>(idx, tok_emb, pos_emb, x16);

    const dim3 gLN(BT / 4);
    const dim3 gAttn(HH, BB);
    const dim3 gQKV(1152 / 64, BT / 64);   // 18 x 256 = 4608 blocks
    const dim3 gD(384 / 64, BT / 64);      // 6 x 256 = 1536 blocks
    const dim3 gFF(1536 / 64, BT / 64);    // 24 x 256 = 6144 blocks
    const dim3 gHead(128 / 64, BT / 64);   // 2 x 256 = 512 blocks

    for (int l = 0; l < LL; ++l) {
        const size_t dOff = (size_t)l * DD;

        ln_k<<<gLN, blk, 0, stream>>>(x16, ln1_w + dOff, ln1_b + dOff, h16);

        // qkv16 = h @ Wqkv (bf16 out)
        gemm64_k<<<gQKV, blk, 0, stream>>>(h16, wqkvT + (size_t)l * 1152 * 384,
                                           nullptr, nullptr, nullptr, qkv16,
                                           BT, 384, 1152, 1152, 0);

        attn_mfma_k<<<gAttn, blk, 0, stream>>>(qkv16, o16);

        // x = x + o @ proj_w + proj_b   (bf16 residual stream)
        gemm64_k<<<gD, blk, 0, stream>>>(o16, projT + (size_t)l * 384 * 384,
                                         proj_b + dOff, x16, nullptr, x16,
                                         BT, 384, 384, 384, 0);

        ln_k<<<gLN, blk, 0, stream>>>(x16, ln2_w + dOff, ln2_b + dOff, h16);

        // ff = relu(h @ W1 + b1) (bf16 out)
        gemm64_k<<<gFF, blk, 0, stream>>>(h16, ff1T + (size_t)l * 1536 * 384,
                                          ff_b1 + (size_t)l * FFD, nullptr,
                                          nullptr, ff16,
                                          BT, 384, 1536, 1536, 1);

        // x = x + ff @ W2 + b2
        gemm64_k<<<gD, blk, 0, stream>>>(ff16, ff2T + (size_t)l * 384 * 1536,
                                         ff_b2 + dOff, x16, nullptr, x16,
                                         BT, 1536, 384, 384, 0);
    }

    ln_k<<<gLN, blk, 0, stream>>>(x16, lnf_w, lnf_b, h16);
    gemm64_k<<<gHead, blk, 0, stream>>>(h16, headT, head_b, nullptr, out, nullptr,
                                        BT, 384, 65, 65, 0);
}